// Round 8
// baseline (132.772 us; speedup 1.0000x reference)
//
#include <hip/hip_runtime.h>

// Problem constants
#define NNODES 64
#define HID 32
#define NFACT 3
#define NE 1024
#define NROWS (NE + NFACT)   // 1027
#define TPB 512
// R21: stage C split into a standalone streaming kernel (K2). K1 (graph
// kernel) ends at stage P writing P1/P2 tables to workspace global (64B/row,
// 8KB/graph -> L1-resident for K2). K1 sheds ~25% of its DS work, the action/
// es/ed loads and 3 of 6 barriers; K2 runs at full wave-slot occupancy with
// zero LDS, L1-hit gathers, no lockstep barriers. Model: kernel was DS+latency
// bound with barrier-synced waves (R15 profile: VALU~48%/DS~50%/nothing
// saturated/occupancy-insensitive).
#define STR 36               // float row stride for xpp
#define QSTRH 20             // u32 row stride for packed-f16 Q rows (16 data + 4 pad)
#define MAXTILES 128         // 16-edge tile capacity (true max = 124)
// gws layout (ints): [0:64) sdeg | [64:128) soff | [128] snt | [256:384) tns
// | [512:2560) pep | weight block:
#define W2OFF 2560           // W2 f16 frags: [s][n32] -> 8 u32
#define WEOFF 3072           // stage-B edge wts: [s] -> 16 u32
#define WPOFF 3104           // stage-P bf16 frags: [g][quad][m16] -> 8 u32
#define WCOFF 4128           // stage-C wlh[16] | wvh[16]
#define WXOFF 4160           // stage-P x-part f32: [g][m16] -> 8 f32
#define WBOFF 4416           // b2 copy (32 f32)
#define GWSN  4448           // total gws ints; gP starts here (16B aligned)

typedef short bf16x8 __attribute__((ext_vector_type(8)));
typedef float f32x4  __attribute__((ext_vector_type(4)));
typedef float f32x16 __attribute__((ext_vector_type(16)));
typedef _Float16 f16x2 __attribute__((ext_vector_type(2)));
typedef _Float16 f16x8 __attribute__((ext_vector_type(8)));

__device__ __forceinline__ unsigned pack_bf2(float lo, float hi) {
    unsigned ul = __builtin_bit_cast(unsigned, lo);
    unsigned uh = __builtin_bit_cast(unsigned, hi);
    ul += 0x7fffu + ((ul >> 16) & 1u);
    uh += 0x7fffu + ((uh >> 16) & 1u);
    return (ul >> 16) | (uh & 0xffff0000u);
}
__device__ __forceinline__ f16x2 pkrtz(float lo, float hi) {
    return __builtin_bit_cast(f16x2, __builtin_amdgcn_cvt_pkrtz(lo, hi));
}
__device__ __forceinline__ unsigned packh2u(float lo, float hi) {
    f16x2 r; r.x = (_Float16)lo; r.y = (_Float16)hi;
    return __builtin_bit_cast(unsigned, r);
}
__device__ __forceinline__ float dot2acc(f16x2 a, f16x2 b, float c) {
#if __has_builtin(__builtin_amdgcn_fdot2)
    return __builtin_amdgcn_fdot2(a, b, c, false);
#else
    return c + (float)a.x * (float)b.x + (float)a.y * (float)b.y;
#endif
}
__device__ __forceinline__ float4 fma4(float a, float4 w, float4 c) {
    c.x = fmaf(a, w.x, c.x); c.y = fmaf(a, w.y, c.y);
    c.z = fmaf(a, w.z, c.z); c.w = fmaf(a, w.w, c.w);
    return c;
}

// ---- pre-kernel: 1 block builds CSR tables + packed weight fragments ----
//   pep packed: low12 = edge id (0xFFF = pad), bits12-17 = dst, bits18-23 = src
__global__ __launch_bounds__(256) void csr_build(
    const int* __restrict__ es, const int* __restrict__ ed,
    const float* __restrict__ W1, const float* __restrict__ W2,
    const float* __restrict__ Wl, const float* __restrict__ Wv,
    const float* __restrict__ b2, int* __restrict__ gws)
{
    const int tid = threadIdx.x;
    __shared__ int sdeg[NNODES], soff[NNODES], scnt[NNODES];
    __shared__ int tns[MAXTILES], snt;
    __shared__ int pep[MAXTILES * 16];
    if (tid < NNODES) { sdeg[tid] = 0; scnt[tid] = 0; }
    if (tid < MAXTILES) tns[tid] = 0;
#pragma unroll
    for (int i = tid; i < MAXTILES * 16; i += 256) pep[i] = 0xFFF;
    int ces[4], ced[4];
#pragma unroll
    for (int i = 0; i < 4; i++) { ces[i] = es[tid + i * 256]; ced[i] = ed[tid + i * 256]; }

    // ---- weight packing (independent of CSR; overlaps the barriers below) ----
    unsigned* gu = (unsigned*)gws;
    float*    gf = (float*)gws;
    if (tid < 64) {              // W2 f16 frags: s=tid>>5, n=tid&31
        const int s = tid >> 5, n = tid & 31;
        unsigned* o = &gu[W2OFF + tid * 8];
#pragma unroll
        for (int j = 0; j < 4; j++) {
            o[j]     = packh2u(W2[(s * 8 + 2 * j) * HID + n],      W2[(s * 8 + 2 * j + 1) * HID + n]);
            o[4 + j] = packh2u(W2[(16 + s * 8 + 2 * j) * HID + n], W2[(16 + s * 8 + 2 * j + 1) * HID + n]);
        }
    } else if (tid < 66) {       // stage-B edge weights: s = tid-64
        const int s = tid - 64;
        unsigned* o = &gu[WEOFF + s * 16];
#pragma unroll
        for (int j = 0; j < 4; j++) {
            o[j]      = packh2u(W1[8 * HID + s * 8 + 2 * j],      W1[8 * HID + s * 8 + 2 * j + 1]);
            o[4 + j]  = packh2u(W1[8 * HID + 16 + s * 8 + 2 * j], W1[8 * HID + 16 + s * 8 + 2 * j + 1]);
            o[8 + j]  = packh2u(W1[9 * HID + s * 8 + 2 * j],      W1[9 * HID + s * 8 + 2 * j + 1]);
            o[12 + j] = packh2u(W1[9 * HID + 16 + s * 8 + 2 * j], W1[9 * HID + 16 + s * 8 + 2 * j + 1]);
        }
    } else if (tid < 82) {       // stage-C wlh/wvh: j = tid-66
        const int j = tid - 66;
        const float* Wl72 = Wl + 72 * HID;
        gu[WCOFF + j]      = packh2u(Wl72[j], Wl72[j + 16]);
        gu[WCOFF + 16 + j] = packh2u(Wv[j],   Wv[j + 16]);
    } else if (tid < 114) {      // b2 copy: i = tid-82
        gf[WBOFF + (tid - 82)] = b2[tid - 82];
    }
    if (tid < 128) {             // stage-P bf16 frags
        const int g = tid >> 6, quad = (tid >> 4) & 3, m = tid & 15;
        const int cbase = g ? 40 : 4;
        const int kh = quad * 8;
        unsigned* o = &gu[WPOFF + tid * 8];
#pragma unroll
        for (int j = 0; j < 4; j++) {
            o[j]     = pack_bf2(Wl[(cbase + kh + 2 * j) * HID + m],      Wl[(cbase + kh + 2 * j + 1) * HID + m]);
            o[4 + j] = pack_bf2(Wl[(cbase + kh + 2 * j) * HID + 16 + m], Wl[(cbase + kh + 2 * j + 1) * HID + 16 + m]);
        }
    } else if (tid < 160) {      // stage-P x-part
        const int g = (tid - 128) >> 4, m = tid & 15;
        const int xbase = g ? 36 : 0;
        float* o = &gf[WXOFF + ((tid - 128)) * 8];
#pragma unroll
        for (int i = 0; i < 4; i++) {
            o[i]     = Wl[(xbase + i) * HID + m];
            o[4 + i] = Wl[(xbase + i) * HID + 16 + m];
        }
    }

    __syncthreads();
#pragma unroll
    for (int i = 0; i < 4; i++) atomicAdd(&sdeg[ces[i]], 1);
    __syncthreads();
    if (tid < NNODES) {          // wave 0 scan
        const int cnt = (sdeg[tid] + 15) >> 4;
        int scan = cnt;
#pragma unroll
        for (int o = 1; o < 64; o <<= 1) {
            const int v = __shfl_up(scan, o);
            if (tid >= o) scan += v;
        }
        const int base = scan - cnt;
        soff[tid] = base;
        if (tid == NNODES - 1) snt = scan;
#pragma unroll 1
        for (int j = 0; j < cnt; j++) tns[base + j] = tid;
    }
    __syncthreads();
#pragma unroll
    for (int i = 0; i < 4; i++) {
        const int n = ces[i];
        const int idx = atomicAdd(&scnt[n], 1);
        pep[soff[n] * 16 + idx] = (tid + i * 256) | (ced[i] << 12) | (n << 18);
    }
    __syncthreads();
    if (tid < NNODES) { gws[tid] = sdeg[tid]; gws[64 + tid] = soff[tid]; }
    if (tid == 0) gws[128] = snt;
    if (tid < MAXTILES) gws[256 + tid] = tns[tid];
#pragma unroll
    for (int i = tid; i < MAXTILES * 16; i += 256) gws[512 + i] = pep[i];
}

// ---- K1: graph kernel (stages A, Q, B, P); writes P tables to gP ----
__global__ __launch_bounds__(TPB, 6) void critic_graph(
    const float* __restrict__ x,
    const float* __restrict__ edge_attr,
    const float* __restrict__ W1,
    const float* __restrict__ b1,
    const float* __restrict__ bl,
    const int*   __restrict__ gws,
    unsigned*    __restrict__ gP)
{
    const int b    = blockIdx.x;
    const int tid  = threadIdx.x;
    const int lane = tid & 63;
    const int wv   = tid >> 6;          // 0..7
    const int quad = lane >> 4;
    const int m16  = lane & 15;
    const f16x2 z2 = { (_Float16)0.f, (_Float16)0.f };
    const unsigned* gu = (const unsigned*)gws;
    const float*    gf = (const float*)gws;

    __shared__ __align__(16) float4 xs4[NNODES];
    __shared__ __align__(16) float  xpp[NNODES * STR];
    __shared__ __align__(16) float  qp0[NNODES * STR];   // f16 Q1 rows
    __shared__ __align__(16) float  qp1[NNODES * STR];   // f16 Q2 rows
    __shared__ __align__(16) float  W1s[8 * HID];
    __shared__ __align__(16) float  eas[NE * 2];         // staged edge_attr (8KB)
    __shared__ float  b1s[HID];

    unsigned* qh0 = (unsigned*)qp0;
    unsigned* qh1 = (unsigned*)qp1;

    // ---- Stage A ----
    if (tid < NNODES) xs4[tid] = ((const float4*)x)[b * NNODES + tid];
    if (tid < 64) ((float4*)W1s)[tid] = ((const float4*)W1)[tid];
    if (tid < HID) b1s[tid] = b1[tid];
    ((float4*)eas)[tid] = ((const float4*)edge_attr)[(size_t)b * (NE / 2) + tid];
    {
        const float4 z4 = make_float4(0.f, 0.f, 0.f, 0.f);
#pragma unroll 1
        for (int i = tid; i < NNODES * STR / 4; i += TPB) ((float4*)xpp)[i] = z4;
    }
    __syncthreads();

    // ---- Stage Q ----
    {
        const int  n  = lane;
        const int  k0 = (wv & 3) * 8;
        const bool g1 = (wv < 4);
        const int  rb = g1 ? 0 : 4;
        const float4 xv = xs4[n];
        float4 qa, qb;
        if (g1) {
            const float4* b1v = (const float4*)&b1s[k0];
            qa = b1v[0]; qb = b1v[1];
        } else {
            qa = make_float4(0.f, 0.f, 0.f, 0.f); qb = qa;
        }
#pragma unroll 1
        for (int i = 0; i < 4; i++) {
            const float xi = (i == 0) ? xv.x : (i == 1) ? xv.y : (i == 2) ? xv.z : xv.w;
            const float4* wa = (const float4*)&W1s[(rb + i) * HID + k0];
            qa = fma4(xi, wa[0], qa); qb = fma4(xi, wa[1], qb);
        }
        uint4 p;
        p.x = __builtin_bit_cast(unsigned, pkrtz(qa.x, qa.y));
        p.y = __builtin_bit_cast(unsigned, pkrtz(qa.z, qa.w));
        p.z = __builtin_bit_cast(unsigned, pkrtz(qb.x, qb.y));
        p.w = __builtin_bit_cast(unsigned, pkrtz(qb.z, qb.w));
        unsigned* dst = g1 ? qh0 : qh1;
        *(uint4*)&dst[n * QSTRH + (wv & 3) * 4] = p;
    }
    __syncthreads();

    // ---- Stage B: pair-tiled f16-MFMA edge messages ----
    {
        const int* gtns = gws + 256;
        const int* gpep = gws + 512;
        const int NW   = TPB / 64;
        const int s    = lane >> 5;
        const int klo2 = s * 4;
        const int n32  = lane & 31;

        const uint4 we0 = *(const uint4*)&gu[WEOFF + s * 16];
        const uint4 we1 = *(const uint4*)&gu[WEOFF + s * 16 + 4];
        const uint4 we2 = *(const uint4*)&gu[WEOFF + s * 16 + 8];
        const uint4 we3 = *(const uint4*)&gu[WEOFF + s * 16 + 12];
        f16x2 w8p[4], w8q[4], w9p[4], w9q[4];
        w8p[0] = __builtin_bit_cast(f16x2, we0.x); w8p[1] = __builtin_bit_cast(f16x2, we0.y);
        w8p[2] = __builtin_bit_cast(f16x2, we0.z); w8p[3] = __builtin_bit_cast(f16x2, we0.w);
        w8q[0] = __builtin_bit_cast(f16x2, we1.x); w8q[1] = __builtin_bit_cast(f16x2, we1.y);
        w8q[2] = __builtin_bit_cast(f16x2, we1.z); w8q[3] = __builtin_bit_cast(f16x2, we1.w);
        w9p[0] = __builtin_bit_cast(f16x2, we2.x); w9p[1] = __builtin_bit_cast(f16x2, we2.y);
        w9p[2] = __builtin_bit_cast(f16x2, we2.z); w9p[3] = __builtin_bit_cast(f16x2, we2.w);
        w9q[0] = __builtin_bit_cast(f16x2, we3.x); w9q[1] = __builtin_bit_cast(f16x2, we3.y);
        w9q[2] = __builtin_bit_cast(f16x2, we3.z); w9q[3] = __builtin_bit_cast(f16x2, we3.w);
        const uint4 wfa = *(const uint4*)&gu[W2OFF + (s * 32 + n32) * 8];
        const uint4 wfb = *(const uint4*)&gu[W2OFF + (s * 32 + n32) * 8 + 4];
        const f16x8 hfA = __builtin_bit_cast(f16x8, wfa);
        const f16x8 hfB = __builtin_bit_cast(f16x8, wfb);

        const int np = (gws[128] + 1) >> 1;

        int p = wv;
        int raw = 0xFFF, tA = 0, tB = 0;
        if (p < np) {
            raw = gpep[p * 32 + n32];
            const int2 tt = *(const int2*)&gtns[2 * p];
            tA = tt.x; tB = tt.y;
        }
#pragma unroll 1
        while (p < np) {
            const int pn = p + NW;
            int rawn = 0xFFF, tAn = 0, tBn = 0;
            if (pn < np) {
                rawn = gpep[pn * 32 + n32];
                const int2 ttn = *(const int2*)&gtns[2 * pn];
                tAn = ttn.x; tBn = ttn.y;
            }
            const int e    = raw & 0xFFF;
            const bool pad = (e == 0xFFF);
            const int d0   = (raw >> 12) & 63;
            const int nd   = (raw >> 18) & 63;
            const float2 ea = *(const float2*)&eas[(pad ? 0 : e) * 2];

            const uint4 A1 = *(const uint4*)&qh0[nd * QSTRH + klo2];
            const uint4 A2 = *(const uint4*)&qh0[nd * QSTRH + 8 + klo2];
            const uint4 G1 = *(const uint4*)&qh1[d0 * QSTRH + klo2];
            const uint4 G2 = *(const uint4*)&qh1[d0 * QSTRH + 8 + klo2];

            const f16x2 ex2 = pkrtz(ea.x, ea.x);
            const f16x2 ey2 = pkrtz(ea.y, ea.y);
            const unsigned pz = pad ? 0u : 0xFFFFFFFFu;

            uint4 pa4, pb4;
#define MSLOT(dst, au, gu_, w8, w9) { \
            f16x2 t = __builtin_bit_cast(f16x2, au) + __builtin_bit_cast(f16x2, gu_); \
            t = __builtin_elementwise_fma(ex2, w8, t); \
            t = __builtin_elementwise_fma(ey2, w9, t); \
            t = __builtin_elementwise_max(t, z2); \
            dst = __builtin_bit_cast(unsigned, t) & pz; }
            MSLOT(pa4.x, A1.x, G1.x, w8p[0], w9p[0])
            MSLOT(pa4.y, A1.y, G1.y, w8p[1], w9p[1])
            MSLOT(pa4.z, A1.z, G1.z, w8p[2], w9p[2])
            MSLOT(pa4.w, A1.w, G1.w, w8p[3], w9p[3])
            MSLOT(pb4.x, A2.x, G2.x, w8q[0], w9q[0])
            MSLOT(pb4.y, A2.y, G2.y, w8q[1], w9q[1])
            MSLOT(pb4.z, A2.z, G2.z, w8q[2], w9q[2])
            MSLOT(pb4.w, A2.w, G2.w, w8q[3], w9q[3])
#undef MSLOT
            const f16x8 afA = __builtin_bit_cast(f16x8, pa4);
            const f16x8 afB = __builtin_bit_cast(f16x8, pb4);

            f32x16 c;
#pragma unroll
            for (int j = 0; j < 16; j++) c[j] = 0.0f;
            c = __builtin_amdgcn_mfma_f32_32x32x16_f16(afA, hfA, c, 0, 0, 0);
            c = __builtin_amdgcn_mfma_f32_32x32x16_f16(afB, hfB, c, 0, 0, 0);

            float sA = ((c[0] + c[1]) + (c[2] + c[3])) + ((c[4] + c[5]) + (c[6] + c[7]));
            float sB = ((c[8] + c[9]) + (c[10] + c[11])) + ((c[12] + c[13]) + (c[14] + c[15]));
            sA += __shfl_xor(sA, 32);
            sB += __shfl_xor(sB, 32);
            const int   nst = (lane < 32) ? tA : tB;
            const float sv  = (lane < 32) ? sA : sB;
            atomicAdd(&xpp[nst * STR + n32], sv);

            p = pn; raw = rawn; tA = tAn; tB = tBn;
        }
    }
    __syncthreads();

    // ---- Stage P: head projections via MFMA; write packed f16 to gP ----
    {
        const bool g1p = (wv < 4);
        const int  g   = g1p ? 0 : 1;
        const int  pidx = ((g * 4 + quad) * 16 + m16) * 8;
        const uint4 bpau = *(const uint4*)&gu[WPOFF + pidx];
        const uint4 bpbu = *(const uint4*)&gu[WPOFF + pidx + 4];
        const bf16x8 bPa = __builtin_bit_cast(bf16x8, bpau);
        const bf16x8 bPb = __builtin_bit_cast(bf16x8, bpbu);
        const float4 wxav = *(const float4*)&gf[WXOFF + (g * 16 + m16) * 8];
        const float4 wxbv = *(const float4*)&gf[WXOFF + (g * 16 + m16) * 8 + 4];
        const float4 b2a = *(const float4*)&gf[WBOFF + quad * 8];
        const float4 b2b = *(const float4*)&gf[WBOFF + quad * 8 + 4];
        const float bca = g1p ? bl[m16] : 0.f;
        const float bcb = g1p ? bl[16 + m16] : 0.f;
        const int   mrow = (wv & 3) * 16 + m16;
        const float dn   = (float)gws[mrow];

        const int kh = quad * 8;
        const float4* xr = (const float4*)&xpp[mrow * STR + kh];
        float4 x0 = xr[0], x1 = xr[1];
        x0.x = fmaf(dn, b2a.x, x0.x); x0.y = fmaf(dn, b2a.y, x0.y);
        x0.z = fmaf(dn, b2a.z, x0.z); x0.w = fmaf(dn, b2a.w, x0.w);
        x1.x = fmaf(dn, b2b.x, x1.x); x1.y = fmaf(dn, b2b.y, x1.y);
        x1.z = fmaf(dn, b2b.z, x1.z); x1.w = fmaf(dn, b2b.w, x1.w);
        uint4 packed;
        packed.x = pack_bf2(x0.x, x0.y);
        packed.y = pack_bf2(x0.z, x0.w);
        packed.z = pack_bf2(x1.x, x1.y);
        packed.w = pack_bf2(x1.z, x1.w);
        const bf16x8 af = __builtin_bit_cast(bf16x8, packed);

        float wxa[4] = { wxav.x, wxav.y, wxav.z, wxav.w };
        float wxb[4] = { wxbv.x, wxbv.y, wxbv.z, wxbv.w };
        f32x4 ca, cb;
#pragma unroll
        for (int r = 0; r < 4; r++) {
            const float4 xv = xs4[(wv & 3) * 16 + quad * 4 + r];
            float a0 = bca, a1 = bcb;
#pragma unroll
            for (int i = 0; i < 4; i++) {
                const float xi = (i == 0) ? xv.x : (i == 1) ? xv.y : (i == 2) ? xv.z : xv.w;
                a0 = fmaf(xi, wxa[i], a0);
                a1 = fmaf(xi, wxb[i], a1);
            }
            ca[r] = a0; cb[r] = a1;
        }
        ca = __builtin_amdgcn_mfma_f32_16x16x32_bf16(af, bPa, ca, 0, 0, 0);
        cb = __builtin_amdgcn_mfma_f32_16x16x32_bf16(af, bPb, cb, 0, 0, 0);

        // gP row layout: u32 slot m16 = f16 pair (col m16, col m16+16)
        unsigned* grow = gP + ((size_t)b * 2 + g) * (NNODES * 16);
#pragma unroll
        for (int r = 0; r < 4; r++) {
            const int row = (wv & 3) * 16 + quad * 4 + r;
            grow[row * 16 + m16] = __builtin_bit_cast(unsigned, pkrtz(ca[r], cb[r]));
        }
    }
}

// ---- K2: streaming value head; zero LDS (except reduce scratch) ----
__global__ __launch_bounds__(TPB, 6) void critic_value(
    const float* __restrict__ action,
    const int*   __restrict__ es,
    const int*   __restrict__ ed,
    const float* __restrict__ bv,
    const int*   __restrict__ gws,
    const unsigned* __restrict__ gP,
    float* __restrict__ out)
{
    const int b   = blockIdx.x;
    const int tid = threadIdx.x;
    const f16x2 z2 = { (_Float16)0.f, (_Float16)0.f };
    const unsigned* gu = (const unsigned*)gws;
    __shared__ float wred[TPB / 64];

    const float* actb = action + (size_t)b * NROWS;
    const float bvv = bv[0];
    const unsigned* P1 = gP + (size_t)b * 2 * (NNODES * 16);
    const unsigned* P2 = P1 + NNODES * 16;

    f16x2 wlh[16], wvh[16];
#pragma unroll
    for (int q = 0; q < 4; q++) {       // lane-uniform dwordx4 loads
        const uint4 ul = *(const uint4*)&gu[WCOFF + q * 4];
        const uint4 uv = *(const uint4*)&gu[WCOFF + 16 + q * 4];
        wlh[q*4+0] = __builtin_bit_cast(f16x2, ul.x); wlh[q*4+1] = __builtin_bit_cast(f16x2, ul.y);
        wlh[q*4+2] = __builtin_bit_cast(f16x2, ul.z); wlh[q*4+3] = __builtin_bit_cast(f16x2, ul.w);
        wvh[q*4+0] = __builtin_bit_cast(f16x2, uv.x); wvh[q*4+1] = __builtin_bit_cast(f16x2, uv.y);
        wvh[q*4+2] = __builtin_bit_cast(f16x2, uv.z); wvh[q*4+3] = __builtin_bit_cast(f16x2, uv.w);
    }

    float vsum = 0.0f;

#define CSLOT(j, pu, qu, acc) { \
    f16x2 t = __builtin_bit_cast(f16x2, pu) + __builtin_bit_cast(f16x2, qu); \
    t = __builtin_elementwise_fma(a2, wlh[j], t); \
    t = __builtin_elementwise_max(t, z2); \
    acc = dot2acc(t, wvh[j], acc); }

#define CROW(na, nb, av) { \
    const unsigned* ra = &P1[(na) * 16]; \
    const unsigned* rb = &P2[(nb) * 16]; \
    const uint4 Pa0 = *(const uint4*)&ra[0]; \
    const uint4 Pa1 = *(const uint4*)&ra[4]; \
    const uint4 Pa2 = *(const uint4*)&ra[8]; \
    const uint4 Pa3 = *(const uint4*)&ra[12]; \
    const uint4 Pb0 = *(const uint4*)&rb[0]; \
    const uint4 Pb1 = *(const uint4*)&rb[4]; \
    const uint4 Pb2 = *(const uint4*)&rb[8]; \
    const uint4 Pb3 = *(const uint4*)&rb[12]; \
    const f16x2 a2 = pkrtz(av, av); \
    float v0 = bvv, v1 = 0.0f; \
    CSLOT( 0, Pa0.x, Pb0.x, v0) CSLOT( 1, Pa0.y, Pb0.y, v1) \
    CSLOT( 2, Pa0.z, Pb0.z, v0) CSLOT( 3, Pa0.w, Pb0.w, v1) \
    CSLOT( 4, Pa1.x, Pb1.x, v0) CSLOT( 5, Pa1.y, Pb1.y, v1) \
    CSLOT( 6, Pa1.z, Pb1.z, v0) CSLOT( 7, Pa1.w, Pb1.w, v1) \
    CSLOT( 8, Pa2.x, Pb2.x, v0) CSLOT( 9, Pa2.y, Pb2.y, v1) \
    CSLOT(10, Pa2.z, Pb2.z, v0) CSLOT(11, Pa2.w, Pb2.w, v1) \
    CSLOT(12, Pa3.x, Pb3.x, v0) CSLOT(13, Pa3.y, Pb3.y, v1) \
    CSLOT(14, Pa3.z, Pb3.z, v0) CSLOT(15, Pa3.w, Pb3.w, v1) \
    vsum += v0 + v1; }

#pragma unroll 1
    for (int i = 0; i < NE / TPB; i++) {
        const int r = tid + i * TPB;
        const int na = es[r], nb = ed[r];
        const float a = actb[r];
        CROW(na, nb, a)
    }
    if (tid < NFACT) {
        const int r = NE + tid;
        const int naf = NNODES - NFACT + tid;
        const float av = actb[r];
        CROW(naf, naf, av)
    }
#undef CROW
#undef CSLOT

#pragma unroll
    for (int off = 32; off > 0; off >>= 1)
        vsum += __shfl_down(vsum, off, 64);
    if ((tid & 63) == 0) wred[tid >> 6] = vsum;
    __syncthreads();
    if (tid == 0) {
        float t = 0.0f;
#pragma unroll
        for (int w = 0; w < TPB / 64; w++) t += wred[w];
        out[b] = t;
    }
}

extern "C" void kernel_launch(void* const* d_in, const int* in_sizes, int n_in,
                              void* d_out, int out_size, void* d_ws, size_t ws_size,
                              hipStream_t stream) {
    const float* x         = (const float*)d_in[0];
    const float* edge_attr = (const float*)d_in[2];
    const float* action    = (const float*)d_in[3];
    const int*   es        = (const int*)d_in[4];
    const int*   ed        = (const int*)d_in[5];
    const float* W1        = (const float*)d_in[6];
    const float* b1        = (const float*)d_in[7];
    const float* W2        = (const float*)d_in[8];
    const float* b2        = (const float*)d_in[9];
    const float* Wl        = (const float*)d_in[10];
    const float* bl        = (const float*)d_in[11];
    const float* Wv        = (const float*)d_in[12];
    const float* bv        = (const float*)d_in[13];
    float* out = (float*)d_out;
    int*      gws = (int*)d_ws;                    // 4448 ints = 17.8KB
    unsigned* gP  = (unsigned*)((int*)d_ws + GWSN); // +8.4MB P tables

    csr_build<<<dim3(1), dim3(256), 0, stream>>>(es, ed, W1, W2, Wl, Wv, b2, gws);
    critic_graph<<<dim3(out_size), dim3(TPB), 0, stream>>>(
        x, edge_attr, W1, b1, bl, gws, gP);
    critic_value<<<dim3(out_size), dim3(TPB), 0, stream>>>(
        action, es, ed, bv, gws, gP, out);
}

// Round 9
// 125.420 us; speedup vs baseline: 1.0586x; 1.0586x over previous
//
#include <hip/hip_runtime.h>

// Problem constants
#define NNODES 64
#define HID 32
#define NFACT 3
#define NE 1024
#define NROWS (NE + NFACT)   // 1027
#define TPB 512              // 8 waves/graph (R14); (512,6) bounds: no spill (R15)
// R18 (best measured, 120.4us harness): CSR in 1-block pre-kernel; edge_attr
// staged to LDS; packed-f16 Q/P storage + pk-f16 math (R17).
// R19 sort / R20 weight-hoist: null. R21 split: +9us, reverted.
// R22 = R18 + (1) removed redundant mid-stage-P barrier (post-B barrier
// already drains all Q reads), (2) action prefetched in stage A (4KB/block,
// touched once -> always cold HBM; was an exposed ~900cy chain at stage C).
#define STR 36               // float row stride for xpp
#define QSTRH 20             // u32 row stride for packed-f16 Q rows (16 data + 4 pad)
#define MAXTILES 128         // 16-edge tile capacity (true max = 124)
#define EPT (NE / TPB)       // 2 edges per thread

typedef short bf16x8 __attribute__((ext_vector_type(8)));
typedef float f32x4  __attribute__((ext_vector_type(4)));
typedef float f32x16 __attribute__((ext_vector_type(16)));
typedef _Float16 f16x2 __attribute__((ext_vector_type(2)));
typedef _Float16 f16x8 __attribute__((ext_vector_type(8)));

// round-to-nearest-even two fp32 -> packed bf16x2 (lo | hi<<16)  [stage P MFMA]
__device__ __forceinline__ unsigned pack_bf2(float lo, float hi) {
    unsigned ul = __builtin_bit_cast(unsigned, lo);
    unsigned uh = __builtin_bit_cast(unsigned, hi);
    ul += 0x7fffu + ((ul >> 16) & 1u);
    uh += 0x7fffu + ((uh >> 16) & 1u);
    return (ul >> 16) | (uh & 0xffff0000u);
}
__device__ __forceinline__ short f2bf(float f) {
    unsigned u = __builtin_bit_cast(unsigned, f);
    u += 0x7fffu + ((u >> 16) & 1u);
    return (short)(u >> 16);
}
// fp32 pair -> packed f16 (RTZ, single v_cvt_pkrtz_f16_f32)
__device__ __forceinline__ f16x2 pkrtz(float lo, float hi) {
    return __builtin_bit_cast(f16x2, __builtin_amdgcn_cvt_pkrtz(lo, hi));
}
// fp32 pair -> packed f16 (RNE, for weights)
__device__ __forceinline__ f16x2 packh2_rne(float lo, float hi) {
    f16x2 r; r.x = (_Float16)lo; r.y = (_Float16)hi; return r;
}
__device__ __forceinline__ float dot2acc(f16x2 a, f16x2 b, float c) {
#if __has_builtin(__builtin_amdgcn_fdot2)
    return __builtin_amdgcn_fdot2(a, b, c, false);
#else
    return c + (float)a.x * (float)b.x + (float)a.y * (float)b.y;
#endif
}
__device__ __forceinline__ float4 fma4(float a, float4 w, float4 c) {
    c.x = fmaf(a, w.x, c.x); c.y = fmaf(a, w.y, c.y);
    c.z = fmaf(a, w.z, c.z); c.w = fmaf(a, w.w, c.w);
    return c;
}

// ---- CSR pre-kernel: 1 block builds the shared edge tiling into d_ws ----
// gws layout (ints): [0:64) sdeg | [64:128) soff | [128] snt | [256:384) tns
//                    | [512:2560) pep
//   pep packed: low12 = edge id (0xFFF = pad), bits12-17 = dst, bits18-23 = src
__global__ __launch_bounds__(256) void csr_build(
    const int* __restrict__ es, const int* __restrict__ ed, int* __restrict__ gws)
{
    const int tid = threadIdx.x;
    __shared__ int sdeg[NNODES], soff[NNODES], scnt[NNODES];
    __shared__ int tns[MAXTILES], snt;
    __shared__ int pep[MAXTILES * 16];
    if (tid < NNODES) { sdeg[tid] = 0; scnt[tid] = 0; }
    if (tid < MAXTILES) tns[tid] = 0;
#pragma unroll
    for (int i = tid; i < MAXTILES * 16; i += 256) pep[i] = 0xFFF;
    int ces[4], ced[4];
#pragma unroll
    for (int i = 0; i < 4; i++) { ces[i] = es[tid + i * 256]; ced[i] = ed[tid + i * 256]; }
    __syncthreads();
#pragma unroll
    for (int i = 0; i < 4; i++) atomicAdd(&sdeg[ces[i]], 1);
    __syncthreads();
    if (tid < NNODES) {          // wave 0 scan
        const int cnt = (sdeg[tid] + 15) >> 4;
        int scan = cnt;
#pragma unroll
        for (int o = 1; o < 64; o <<= 1) {
            const int v = __shfl_up(scan, o);
            if (tid >= o) scan += v;
        }
        const int base = scan - cnt;
        soff[tid] = base;
        if (tid == NNODES - 1) snt = scan;
#pragma unroll 1
        for (int j = 0; j < cnt; j++) tns[base + j] = tid;
    }
    __syncthreads();
#pragma unroll
    for (int i = 0; i < 4; i++) {
        const int n = ces[i];
        const int idx = atomicAdd(&scnt[n], 1);
        pep[soff[n] * 16 + idx] = (tid + i * 256) | (ced[i] << 12) | (n << 18);
    }
    __syncthreads();
    if (tid < NNODES) { gws[tid] = sdeg[tid]; gws[64 + tid] = soff[tid]; }
    if (tid == 0) gws[128] = snt;
    if (tid < MAXTILES) gws[256 + tid] = tns[tid];
#pragma unroll
    for (int i = tid; i < MAXTILES * 16; i += 256) gws[512 + i] = pep[i];
}

__global__ __launch_bounds__(TPB, 6) void critic_fused(
    const float* __restrict__ x,
    const float* __restrict__ edge_attr,
    const float* __restrict__ action,
    const int*   __restrict__ es,
    const int*   __restrict__ ed,
    const float* __restrict__ W1,
    const float* __restrict__ b1,
    const float* __restrict__ W2,
    const float* __restrict__ b2,
    const float* __restrict__ Wl,
    const float* __restrict__ bl,
    const float* __restrict__ Wv,
    const float* __restrict__ bv,
    const int*   __restrict__ gws,
    float* __restrict__ out)
{
    const int b    = blockIdx.x;
    const int tid  = threadIdx.x;
    const int lane = tid & 63;
    const int wv   = tid >> 6;          // 0..7
    const int quad = lane >> 4;
    const int m16  = lane & 15;
    const int kh   = quad * 8;
    const f16x2 z2 = { (_Float16)0.f, (_Float16)0.f };

    __shared__ __align__(16) float4 xs4[NNODES];
    __shared__ __align__(16) float  xpp[NNODES * STR];
    __shared__ __align__(16) float  qp0[NNODES * STR];   // f16 Q1 rows, then f16 P1 rows
    __shared__ __align__(16) float  qp1[NNODES * STR];   // f16 Q2 rows, then f16 P2 rows
    __shared__ __align__(16) float  W1s[10 * HID];
    __shared__ __align__(16) float  eas[NE * 2];         // staged edge_attr (8KB)
    __shared__ float  b1s[HID];
    __shared__ float  wred[TPB / 64];

    unsigned* qh0 = (unsigned*)qp0;   // packed-f16 rows: stride QSTRH u32
    unsigned* qh1 = (unsigned*)qp1;

    // ---- Stage A: stage x + W1 + edge_attr, zero xpp; prefetch edges+action ----
    if (tid < NNODES) xs4[tid] = ((const float4*)x)[b * NNODES + tid];
    if (tid < 80) ((float4*)W1s)[tid] = ((const float4*)W1)[tid];
    if (tid < HID) b1s[tid] = b1[tid];
    ((float4*)eas)[tid] = ((const float4*)edge_attr)[(size_t)b * (NE / 2) + tid]; // 512 f4
    {   // vectorized xpp zero: 2304 floats = 576 float4 slots
        const float4 z4 = make_float4(0.f, 0.f, 0.f, 0.f);
#pragma unroll 1
        for (int i = tid; i < NNODES * STR / 4; i += TPB) ((float4*)xpp)[i] = z4;
    }

    // cache this thread's 2 edges + action values in registers (coalesced,
    // issued here so the cold-HBM action latency hides under stages Q/B)
    const float* actb = action + (size_t)b * NROWS;
    int   ces[EPT], ced[EPT];
    float cact[EPT];
#pragma unroll
    for (int i = 0; i < EPT; i++) {
        ces[i]  = es[tid + i * TPB];
        ced[i]  = ed[tid + i * TPB];
        cact[i] = actb[tid + i * TPB];
    }
    const float cactf = (tid < NFACT) ? actb[NE + tid] : 0.0f;
    __syncthreads();

    // ---- Stage Q: waves 0-3: Q1 (W1 rows 0-3 + b1), waves 4-7: Q2 (rows 4-7) ----
    {
        const int  n  = lane;
        const int  k0 = (wv & 3) * 8;
        const bool g1 = (wv < 4);
        const int  rb = g1 ? 0 : 4;
        const float4 xv = xs4[n];
        float4 qa, qb;
        if (g1) {
            const float4* b1v = (const float4*)&b1s[k0];
            qa = b1v[0]; qb = b1v[1];
        } else {
            qa = make_float4(0.f, 0.f, 0.f, 0.f); qb = qa;
        }
#pragma unroll 1
        for (int i = 0; i < 4; i++) {
            const float xi = (i == 0) ? xv.x : (i == 1) ? xv.y : (i == 2) ? xv.z : xv.w;
            const float4* wa = (const float4*)&W1s[(rb + i) * HID + k0];
            qa = fma4(xi, wa[0], qa); qb = fma4(xi, wa[1], qb);
        }
        uint4 p;   // pack 8 fp32 -> 4 u32 (f16 pairs), one b128 write
        p.x = __builtin_bit_cast(unsigned, pkrtz(qa.x, qa.y));
        p.y = __builtin_bit_cast(unsigned, pkrtz(qa.z, qa.w));
        p.z = __builtin_bit_cast(unsigned, pkrtz(qb.x, qb.y));
        p.w = __builtin_bit_cast(unsigned, pkrtz(qb.z, qb.w));
        unsigned* dst = g1 ? qh0 : qh1;
        *(uint4*)&dst[n * QSTRH + (wv & 3) * 4] = p;
    }
    __syncthreads();

    // ---- Stage B: pair-tiled f16-MFMA edge messages, pep/tns prefetched ----
    {
        const int* gtns = gws + 256;
        const int* gpep = gws + 512;
        const int NW   = TPB / 64;             // 8 waves
        const int klo  = (lane >> 5) * 8;      // K-slice base (0 or 8)
        const int klo2 = klo >> 1;             // u32 offset of the slice
        const int n32  = lane & 31;

        // edge-attr weights as packed f16 pairs (cols klo+2j, klo+2j+1)
        f16x2 w8p[4], w8q[4], w9p[4], w9q[4];
#pragma unroll
        for (int j = 0; j < 4; j++) {
            w8p[j] = packh2_rne(W1s[8 * HID + klo + 2 * j],      W1s[8 * HID + klo + 2 * j + 1]);
            w8q[j] = packh2_rne(W1s[8 * HID + 16 + klo + 2 * j], W1s[8 * HID + 16 + klo + 2 * j + 1]);
            w9p[j] = packh2_rne(W1s[9 * HID + klo + 2 * j],      W1s[9 * HID + klo + 2 * j + 1]);
            w9q[j] = packh2_rne(W1s[9 * HID + 16 + klo + 2 * j], W1s[9 * HID + 16 + klo + 2 * j + 1]);
        }
        f16x8 hfA, hfB;   // W2 B-frags: B[k][n32], K-halves 0..15 / 16..31
#pragma unroll
        for (int j = 0; j < 8; j++) {
            hfA[j] = (_Float16)W2[(klo + j) * HID + n32];
            hfB[j] = (_Float16)W2[(16 + klo + j) * HID + n32];
        }

        const int np = (gws[128] + 1) >> 1;

        int p = wv;
        int raw = 0xFFF, tA = 0, tB = 0;
        if (p < np) {
            raw = gpep[p * 32 + n32];
            const int2 tt = *(const int2*)&gtns[2 * p];
            tA = tt.x; tB = tt.y;
        }
#pragma unroll 1
        while (p < np) {
            const int pn = p + NW;
            int rawn = 0xFFF, tAn = 0, tBn = 0;
            if (pn < np) {                       // prefetch next iter (L2-hot)
                rawn = gpep[pn * 32 + n32];
                const int2 ttn = *(const int2*)&gtns[2 * pn];
                tAn = ttn.x; tBn = ttn.y;
            }
            const int e    = raw & 0xFFF;
            const bool pad = (e == 0xFFF);
            const int d0   = (raw >> 12) & 63;
            const int nd   = (raw >> 18) & 63;
            const float2 ea = *(const float2*)&eas[(pad ? 0 : e) * 2];   // LDS

            // packed-f16 gathers: 4 x b128 total
            const uint4 A1 = *(const uint4*)&qh0[nd * QSTRH + klo2];
            const uint4 A2 = *(const uint4*)&qh0[nd * QSTRH + 8 + klo2];
            const uint4 G1 = *(const uint4*)&qh1[d0 * QSTRH + klo2];
            const uint4 G2 = *(const uint4*)&qh1[d0 * QSTRH + 8 + klo2];

            const f16x2 ex2 = pkrtz(ea.x, ea.x);
            const f16x2 ey2 = pkrtz(ea.y, ea.y);
            const unsigned pz = pad ? 0u : 0xFFFFFFFFu;

            uint4 pa4, pb4;
#define MSLOT(dst, au, gu, w8, w9) { \
            f16x2 t = __builtin_bit_cast(f16x2, au) + __builtin_bit_cast(f16x2, gu); \
            t = __builtin_elementwise_fma(ex2, w8, t); \
            t = __builtin_elementwise_fma(ey2, w9, t); \
            t = __builtin_elementwise_max(t, z2); \
            dst = __builtin_bit_cast(unsigned, t) & pz; }
            MSLOT(pa4.x, A1.x, G1.x, w8p[0], w9p[0])
            MSLOT(pa4.y, A1.y, G1.y, w8p[1], w9p[1])
            MSLOT(pa4.z, A1.z, G1.z, w8p[2], w9p[2])
            MSLOT(pa4.w, A1.w, G1.w, w8p[3], w9p[3])
            MSLOT(pb4.x, A2.x, G2.x, w8q[0], w9q[0])
            MSLOT(pb4.y, A2.y, G2.y, w8q[1], w9q[1])
            MSLOT(pb4.z, A2.z, G2.z, w8q[2], w9q[2])
            MSLOT(pb4.w, A2.w, G2.w, w8q[3], w9q[3])
#undef MSLOT
            const f16x8 afA = __builtin_bit_cast(f16x8, pa4);
            const f16x8 afB = __builtin_bit_cast(f16x8, pb4);

            f32x16 c;
#pragma unroll
            for (int j = 0; j < 16; j++) c[j] = 0.0f;
            c = __builtin_amdgcn_mfma_f32_32x32x16_f16(afA, hfA, c, 0, 0, 0);
            c = __builtin_amdgcn_mfma_f32_32x32x16_f16(afB, hfB, c, 0, 0, 0);

            // C: col=lane&31, row=(reg&3)+8*(reg>>2)+4*(lane>>5).
            float sA = ((c[0] + c[1]) + (c[2] + c[3])) + ((c[4] + c[5]) + (c[6] + c[7]));
            float sB = ((c[8] + c[9]) + (c[10] + c[11])) + ((c[12] + c[13]) + (c[14] + c[15]));
            sA += __shfl_xor(sA, 32);
            sB += __shfl_xor(sB, 32);
            const int   nst = (lane < 32) ? tA : tB;
            const float sv  = (lane < 32) ? sA : sB;
            atomicAdd(&xpp[nst * STR + n32], sv);

            p = pn; raw = rawn; tA = tAn; tB = tBn;
        }
    }
    __syncthreads();

    // ---- Stage-P constants (loaded after B to keep stage-B VGPR peak low) ----
    // waves 0-3 produce P1 (Wl[0:36], +bl), waves 4-7 produce P2 (Wl[36:72])
    const bool g1p   = (wv < 4);
    const int  cbase = g1p ? 4 : 40;
    const int  xbase = g1p ? 0 : 36;
    bf16x8 bPa, bPb;
#pragma unroll
    for (int j = 0; j < 8; j++) {
        bPa[j] = f2bf(Wl[(cbase + kh + j) * HID + m16]);
        bPb[j] = f2bf(Wl[(cbase + kh + j) * HID + 16 + m16]);
    }
    float wxa[4], wxb[4];
#pragma unroll
    for (int i = 0; i < 4; i++) {
        wxa[i] = Wl[(xbase + i) * HID + m16];
        wxb[i] = Wl[(xbase + i) * HID + 16 + m16];
    }
    const float bca = g1p ? bl[m16] : 0.f;
    const float bcb = g1p ? bl[16 + m16] : 0.f;
    float b2k[8];
#pragma unroll
    for (int j = 0; j < 8; j++) b2k[j] = b2[kh + j];
    const int   mrow = (wv & 3) * 16 + m16;
    const float dn   = (float)gws[mrow];        // degree from pre-kernel

    // ---- Stage P: head projections via MFMA; outputs packed f16 (cols k,k+16) ----
    // NOTE (R22): no barrier needed before the qh overwrite — the post-stage-B
    // __syncthreads() already guarantees every wave's Q-table reads are drained.
    {
        const float4* xr = (const float4*)&xpp[mrow * STR + kh];
        float4 x0 = xr[0], x1 = xr[1];
        x0.x = fmaf(dn, b2k[0], x0.x); x0.y = fmaf(dn, b2k[1], x0.y);
        x0.z = fmaf(dn, b2k[2], x0.z); x0.w = fmaf(dn, b2k[3], x0.w);
        x1.x = fmaf(dn, b2k[4], x1.x); x1.y = fmaf(dn, b2k[5], x1.y);
        x1.z = fmaf(dn, b2k[6], x1.z); x1.w = fmaf(dn, b2k[7], x1.w);
        uint4 packed;
        packed.x = pack_bf2(x0.x, x0.y);
        packed.y = pack_bf2(x0.z, x0.w);
        packed.z = pack_bf2(x1.x, x1.y);
        packed.w = pack_bf2(x1.z, x1.w);
        const bf16x8 af = __builtin_bit_cast(bf16x8, packed);

        f32x4 ca, cb;
#pragma unroll
        for (int r = 0; r < 4; r++) {
            const float4 xv = xs4[(wv & 3) * 16 + quad * 4 + r];
            float a0 = bca, a1 = bcb;
#pragma unroll
            for (int i = 0; i < 4; i++) {
                const float xi = (i == 0) ? xv.x : (i == 1) ? xv.y : (i == 2) ? xv.z : xv.w;
                a0 = fmaf(xi, wxa[i], a0);
                a1 = fmaf(xi, wxb[i], a1);
            }
            ca[r] = a0; cb[r] = a1;
        }
        ca = __builtin_amdgcn_mfma_f32_16x16x32_bf16(af, bPa, ca, 0, 0, 0);
        cb = __builtin_amdgcn_mfma_f32_16x16x32_bf16(af, bPb, cb, 0, 0, 0);

        // P row layout: u32 slot m16 of row holds f16 pair (col m16, col m16+16)
        unsigned* dsth = g1p ? qh0 : qh1;
#pragma unroll
        for (int r = 0; r < 4; r++) {
            const int row = (wv & 3) * 16 + quad * 4 + r;
            dsth[row * QSTRH + m16] = __builtin_bit_cast(unsigned, pkrtz(ca[r], cb[r]));
        }
    }
    __syncthreads();

    // ---- Stage C: per-row combine + value head (packed f16 + dot2) ----
    float vsum = 0.0f;
    {
        const float bvv = bv[0];
        const float* Wl72 = Wl + 72 * HID;
        f16x2 wlh[16], wvh[16];
#pragma unroll
        for (int j = 0; j < 16; j++) {
            wlh[j] = packh2_rne(Wl72[j], Wl72[j + 16]);
            wvh[j] = packh2_rne(Wv[j],  Wv[j + 16]);
        }

#define CSLOT(j, pu, qu, acc) { \
        f16x2 t = __builtin_bit_cast(f16x2, pu) + __builtin_bit_cast(f16x2, qu); \
        t = __builtin_elementwise_fma(a2, wlh[j], t); \
        t = __builtin_elementwise_max(t, z2); \
        acc = dot2acc(t, wvh[j], acc); }

#define CROW(na, nb, av) { \
        const unsigned* ra = &qh0[(na) * QSTRH]; \
        const unsigned* rb = &qh1[(nb) * QSTRH]; \
        const uint4 Pa0 = *(const uint4*)&ra[0]; \
        const uint4 Pa1 = *(const uint4*)&ra[4]; \
        const uint4 Pa2 = *(const uint4*)&ra[8]; \
        const uint4 Pa3 = *(const uint4*)&ra[12]; \
        const uint4 Pb0 = *(const uint4*)&rb[0]; \
        const uint4 Pb1 = *(const uint4*)&rb[4]; \
        const uint4 Pb2 = *(const uint4*)&rb[8]; \
        const uint4 Pb3 = *(const uint4*)&rb[12]; \
        const f16x2 a2 = pkrtz(av, av); \
        float v0 = bvv, v1 = 0.0f; \
        CSLOT( 0, Pa0.x, Pb0.x, v0) CSLOT( 1, Pa0.y, Pb0.y, v1) \
        CSLOT( 2, Pa0.z, Pb0.z, v0) CSLOT( 3, Pa0.w, Pb0.w, v1) \
        CSLOT( 4, Pa1.x, Pb1.x, v0) CSLOT( 5, Pa1.y, Pb1.y, v1) \
        CSLOT( 6, Pa1.z, Pb1.z, v0) CSLOT( 7, Pa1.w, Pb1.w, v1) \
        CSLOT( 8, Pa2.x, Pb2.x, v0) CSLOT( 9, Pa2.y, Pb2.y, v1) \
        CSLOT(10, Pa2.z, Pb2.z, v0) CSLOT(11, Pa2.w, Pb2.w, v1) \
        CSLOT(12, Pa3.x, Pb3.x, v0) CSLOT(13, Pa3.y, Pb3.y, v1) \
        CSLOT(14, Pa3.z, Pb3.z, v0) CSLOT(15, Pa3.w, Pb3.w, v1) \
        vsum += v0 + v1; }

#pragma unroll 1
        for (int i = 0; i < EPT; i++) {
            CROW(ces[i], ced[i], cact[i])
        }
        // factory rows 1024..1026 (na == nb)
        if (tid < NFACT) {
            const int naf = NNODES - NFACT + tid;
            CROW(naf, naf, cactf)
        }
#undef CROW
#undef CSLOT
    }

    // ---- block reduction ----
#pragma unroll
    for (int off = 32; off > 0; off >>= 1)
        vsum += __shfl_down(vsum, off, 64);
    if ((tid & 63) == 0) wred[tid >> 6] = vsum;
    __syncthreads();
    if (tid == 0) {
        float t = 0.0f;
#pragma unroll
        for (int w = 0; w < TPB / 64; w++) t += wred[w];
        out[b] = t;
    }
}

extern "C" void kernel_launch(void* const* d_in, const int* in_sizes, int n_in,
                              void* d_out, int out_size, void* d_ws, size_t ws_size,
                              hipStream_t stream) {
    const float* x         = (const float*)d_in[0];
    const float* edge_attr = (const float*)d_in[2];
    const float* action    = (const float*)d_in[3];
    const int*   es        = (const int*)d_in[4];
    const int*   ed        = (const int*)d_in[5];
    const float* W1        = (const float*)d_in[6];
    const float* b1        = (const float*)d_in[7];
    const float* W2        = (const float*)d_in[8];
    const float* b2        = (const float*)d_in[9];
    const float* Wl        = (const float*)d_in[10];
    const float* bl        = (const float*)d_in[11];
    const float* Wv        = (const float*)d_in[12];
    const float* bv        = (const float*)d_in[13];
    float* out = (float*)d_out;
    int*   gws = (int*)d_ws;   // needs 2560 ints = 10.2KB

    csr_build<<<dim3(1), dim3(256), 0, stream>>>(es, ed, gws);
    critic_fused<<<dim3(out_size), dim3(TPB), 0, stream>>>(
        x, edge_attr, action, es, ed, W1, b1, W2, b2, Wl, bl, Wv, bv, gws, out);
}

// Round 10
// 122.145 us; speedup vs baseline: 1.0870x; 1.0268x over previous
//
#include <hip/hip_runtime.h>

// Problem constants
#define NNODES 64
#define HID 32
#define NFACT 3
#define NE 1024
#define NROWS (NE + NFACT)   // 1027
#define TPB 512              // 8 waves/graph (R14); (512,6) bounds: no spill (R15)
// R18 (best measured, 120.4us harness): CSR hoisted to a 1-block pre-kernel
// (edge list is graph-invariant); edge_attr staged to LDS; packed-f16 Q/P
// storage + v_pk_*_f16 math (R17, the one confirmed real win: -6us).
// Locked in as final: R19 (source-sorted C), R20 (weight-pack hoist),
// R21 (kernel fission, +9), R22 (barrier removal + action prefetch, +5/noise)
// all landed at-or-above R18 within the harness's +/-3-4us noise band.
// Regime at convergence: VALU ~48%, DS ~50-60% (modeled), MFMA 3%,
// occupancy-insensitive (R15) -- a latency-structure floor, not a pipe
// roofline; remaining identified slack (~33% stage-B tile padding, ~4-5us)
// is below the bench's noise resolution.
#define STR 36               // float row stride for xpp
#define QSTRH 20             // u32 row stride for packed-f16 Q rows (16 data + 4 pad)
#define MAXTILES 128         // 16-edge tile capacity (true max = 124)
#define EPT (NE / TPB)       // 2 edges per thread

typedef short bf16x8 __attribute__((ext_vector_type(8)));
typedef float f32x4  __attribute__((ext_vector_type(4)));
typedef float f32x16 __attribute__((ext_vector_type(16)));
typedef _Float16 f16x2 __attribute__((ext_vector_type(2)));
typedef _Float16 f16x8 __attribute__((ext_vector_type(8)));

// round-to-nearest-even two fp32 -> packed bf16x2 (lo | hi<<16)  [stage P MFMA]
__device__ __forceinline__ unsigned pack_bf2(float lo, float hi) {
    unsigned ul = __builtin_bit_cast(unsigned, lo);
    unsigned uh = __builtin_bit_cast(unsigned, hi);
    ul += 0x7fffu + ((ul >> 16) & 1u);
    uh += 0x7fffu + ((uh >> 16) & 1u);
    return (ul >> 16) | (uh & 0xffff0000u);
}
__device__ __forceinline__ short f2bf(float f) {
    unsigned u = __builtin_bit_cast(unsigned, f);
    u += 0x7fffu + ((u >> 16) & 1u);
    return (short)(u >> 16);
}
// fp32 pair -> packed f16 (RTZ, single v_cvt_pkrtz_f16_f32)
__device__ __forceinline__ f16x2 pkrtz(float lo, float hi) {
    return __builtin_bit_cast(f16x2, __builtin_amdgcn_cvt_pkrtz(lo, hi));
}
// fp32 pair -> packed f16 (RNE, for weights)
__device__ __forceinline__ f16x2 packh2_rne(float lo, float hi) {
    f16x2 r; r.x = (_Float16)lo; r.y = (_Float16)hi; return r;
}
__device__ __forceinline__ float dot2acc(f16x2 a, f16x2 b, float c) {
#if __has_builtin(__builtin_amdgcn_fdot2)
    return __builtin_amdgcn_fdot2(a, b, c, false);
#else
    return c + (float)a.x * (float)b.x + (float)a.y * (float)b.y;
#endif
}
__device__ __forceinline__ float4 fma4(float a, float4 w, float4 c) {
    c.x = fmaf(a, w.x, c.x); c.y = fmaf(a, w.y, c.y);
    c.z = fmaf(a, w.z, c.z); c.w = fmaf(a, w.w, c.w);
    return c;
}

// ---- CSR pre-kernel: 1 block builds the shared edge tiling into d_ws ----
// gws layout (ints): [0:64) sdeg | [64:128) soff | [128] snt | [256:384) tns
//                    | [512:2560) pep
//   pep packed: low12 = edge id (0xFFF = pad), bits12-17 = dst, bits18-23 = src
__global__ __launch_bounds__(256) void csr_build(
    const int* __restrict__ es, const int* __restrict__ ed, int* __restrict__ gws)
{
    const int tid = threadIdx.x;
    __shared__ int sdeg[NNODES], soff[NNODES], scnt[NNODES];
    __shared__ int tns[MAXTILES], snt;
    __shared__ int pep[MAXTILES * 16];
    if (tid < NNODES) { sdeg[tid] = 0; scnt[tid] = 0; }
    if (tid < MAXTILES) tns[tid] = 0;
#pragma unroll
    for (int i = tid; i < MAXTILES * 16; i += 256) pep[i] = 0xFFF;
    int ces[4], ced[4];
#pragma unroll
    for (int i = 0; i < 4; i++) { ces[i] = es[tid + i * 256]; ced[i] = ed[tid + i * 256]; }
    __syncthreads();
#pragma unroll
    for (int i = 0; i < 4; i++) atomicAdd(&sdeg[ces[i]], 1);
    __syncthreads();
    if (tid < NNODES) {          // wave 0 scan
        const int cnt = (sdeg[tid] + 15) >> 4;
        int scan = cnt;
#pragma unroll
        for (int o = 1; o < 64; o <<= 1) {
            const int v = __shfl_up(scan, o);
            if (tid >= o) scan += v;
        }
        const int base = scan - cnt;
        soff[tid] = base;
        if (tid == NNODES - 1) snt = scan;
#pragma unroll 1
        for (int j = 0; j < cnt; j++) tns[base + j] = tid;
    }
    __syncthreads();
#pragma unroll
    for (int i = 0; i < 4; i++) {
        const int n = ces[i];
        const int idx = atomicAdd(&scnt[n], 1);
        pep[soff[n] * 16 + idx] = (tid + i * 256) | (ced[i] << 12) | (n << 18);
    }
    __syncthreads();
    if (tid < NNODES) { gws[tid] = sdeg[tid]; gws[64 + tid] = soff[tid]; }
    if (tid == 0) gws[128] = snt;
    if (tid < MAXTILES) gws[256 + tid] = tns[tid];
#pragma unroll
    for (int i = tid; i < MAXTILES * 16; i += 256) gws[512 + i] = pep[i];
}

__global__ __launch_bounds__(TPB, 6) void critic_fused(
    const float* __restrict__ x,
    const float* __restrict__ edge_attr,
    const float* __restrict__ action,
    const int*   __restrict__ es,
    const int*   __restrict__ ed,
    const float* __restrict__ W1,
    const float* __restrict__ b1,
    const float* __restrict__ W2,
    const float* __restrict__ b2,
    const float* __restrict__ Wl,
    const float* __restrict__ bl,
    const float* __restrict__ Wv,
    const float* __restrict__ bv,
    const int*   __restrict__ gws,
    float* __restrict__ out)
{
    const int b    = blockIdx.x;
    const int tid  = threadIdx.x;
    const int lane = tid & 63;
    const int wv   = tid >> 6;          // 0..7
    const int quad = lane >> 4;
    const int m16  = lane & 15;
    const int kh   = quad * 8;
    const f16x2 z2 = { (_Float16)0.f, (_Float16)0.f };

    __shared__ __align__(16) float4 xs4[NNODES];
    __shared__ __align__(16) float  xpp[NNODES * STR];
    __shared__ __align__(16) float  qp0[NNODES * STR];   // f16 Q1 rows, then f16 P1 rows
    __shared__ __align__(16) float  qp1[NNODES * STR];   // f16 Q2 rows, then f16 P2 rows
    __shared__ __align__(16) float  W1s[10 * HID];
    __shared__ __align__(16) float  eas[NE * 2];         // staged edge_attr (8KB)
    __shared__ float  b1s[HID];
    __shared__ float  wred[TPB / 64];

    unsigned* qh0 = (unsigned*)qp0;   // packed-f16 rows: stride QSTRH u32
    unsigned* qh1 = (unsigned*)qp1;

    // ---- Stage A: stage x + W1 + edge_attr, zero xpp ----
    if (tid < NNODES) xs4[tid] = ((const float4*)x)[b * NNODES + tid];
    if (tid < 80) ((float4*)W1s)[tid] = ((const float4*)W1)[tid];
    if (tid < HID) b1s[tid] = b1[tid];
    ((float4*)eas)[tid] = ((const float4*)edge_attr)[(size_t)b * (NE / 2) + tid]; // 512 f4
    {   // vectorized xpp zero: 2304 floats = 576 float4 slots
        const float4 z4 = make_float4(0.f, 0.f, 0.f, 0.f);
#pragma unroll 1
        for (int i = tid; i < NNODES * STR / 4; i += TPB) ((float4*)xpp)[i] = z4;
    }

    // cache this thread's 2 edges in registers (coalesced; used in stage C)
    int ces[EPT], ced[EPT];
#pragma unroll
    for (int i = 0; i < EPT; i++) {
        ces[i] = es[tid + i * TPB];
        ced[i] = ed[tid + i * TPB];
    }
    __syncthreads();

    // ---- Stage Q: waves 0-3: Q1 (W1 rows 0-3 + b1), waves 4-7: Q2 (rows 4-7) ----
    {
        const int  n  = lane;
        const int  k0 = (wv & 3) * 8;
        const bool g1 = (wv < 4);
        const int  rb = g1 ? 0 : 4;
        const float4 xv = xs4[n];
        float4 qa, qb;
        if (g1) {
            const float4* b1v = (const float4*)&b1s[k0];
            qa = b1v[0]; qb = b1v[1];
        } else {
            qa = make_float4(0.f, 0.f, 0.f, 0.f); qb = qa;
        }
#pragma unroll 1
        for (int i = 0; i < 4; i++) {
            const float xi = (i == 0) ? xv.x : (i == 1) ? xv.y : (i == 2) ? xv.z : xv.w;
            const float4* wa = (const float4*)&W1s[(rb + i) * HID + k0];
            qa = fma4(xi, wa[0], qa); qb = fma4(xi, wa[1], qb);
        }
        uint4 p;   // pack 8 fp32 -> 4 u32 (f16 pairs), one b128 write
        p.x = __builtin_bit_cast(unsigned, pkrtz(qa.x, qa.y));
        p.y = __builtin_bit_cast(unsigned, pkrtz(qa.z, qa.w));
        p.z = __builtin_bit_cast(unsigned, pkrtz(qb.x, qb.y));
        p.w = __builtin_bit_cast(unsigned, pkrtz(qb.z, qb.w));
        unsigned* dst = g1 ? qh0 : qh1;
        *(uint4*)&dst[n * QSTRH + (wv & 3) * 4] = p;
    }
    __syncthreads();

    // ---- Stage B: pair-tiled f16-MFMA edge messages, pep/tns prefetched ----
    {
        const int* gtns = gws + 256;
        const int* gpep = gws + 512;
        const int NW   = TPB / 64;             // 8 waves
        const int klo  = (lane >> 5) * 8;      // K-slice base (0 or 8)
        const int klo2 = klo >> 1;             // u32 offset of the slice
        const int n32  = lane & 31;

        // edge-attr weights as packed f16 pairs (cols klo+2j, klo+2j+1)
        f16x2 w8p[4], w8q[4], w9p[4], w9q[4];
#pragma unroll
        for (int j = 0; j < 4; j++) {
            w8p[j] = packh2_rne(W1s[8 * HID + klo + 2 * j],      W1s[8 * HID + klo + 2 * j + 1]);
            w8q[j] = packh2_rne(W1s[8 * HID + 16 + klo + 2 * j], W1s[8 * HID + 16 + klo + 2 * j + 1]);
            w9p[j] = packh2_rne(W1s[9 * HID + klo + 2 * j],      W1s[9 * HID + klo + 2 * j + 1]);
            w9q[j] = packh2_rne(W1s[9 * HID + 16 + klo + 2 * j], W1s[9 * HID + 16 + klo + 2 * j + 1]);
        }
        f16x8 hfA, hfB;   // W2 B-frags: B[k][n32], K-halves 0..15 / 16..31
#pragma unroll
        for (int j = 0; j < 8; j++) {
            hfA[j] = (_Float16)W2[(klo + j) * HID + n32];
            hfB[j] = (_Float16)W2[(16 + klo + j) * HID + n32];
        }

        const int np = (gws[128] + 1) >> 1;

        int p = wv;
        int raw = 0xFFF, tA = 0, tB = 0;
        if (p < np) {
            raw = gpep[p * 32 + n32];
            const int2 tt = *(const int2*)&gtns[2 * p];
            tA = tt.x; tB = tt.y;
        }
#pragma unroll 1
        while (p < np) {
            const int pn = p + NW;
            int rawn = 0xFFF, tAn = 0, tBn = 0;
            if (pn < np) {                       // prefetch next iter (L2-hot)
                rawn = gpep[pn * 32 + n32];
                const int2 ttn = *(const int2*)&gtns[2 * pn];
                tAn = ttn.x; tBn = ttn.y;
            }
            const int e    = raw & 0xFFF;
            const bool pad = (e == 0xFFF);
            const int d0   = (raw >> 12) & 63;
            const int nd   = (raw >> 18) & 63;
            const float2 ea = *(const float2*)&eas[(pad ? 0 : e) * 2];   // LDS

            // packed-f16 gathers: 4 x b128 total
            const uint4 A1 = *(const uint4*)&qh0[nd * QSTRH + klo2];
            const uint4 A2 = *(const uint4*)&qh0[nd * QSTRH + 8 + klo2];
            const uint4 G1 = *(const uint4*)&qh1[d0 * QSTRH + klo2];
            const uint4 G2 = *(const uint4*)&qh1[d0 * QSTRH + 8 + klo2];

            const f16x2 ex2 = pkrtz(ea.x, ea.x);
            const f16x2 ey2 = pkrtz(ea.y, ea.y);
            const unsigned pz = pad ? 0u : 0xFFFFFFFFu;

            uint4 pa4, pb4;
#define MSLOT(dst, au, gu, w8, w9) { \
            f16x2 t = __builtin_bit_cast(f16x2, au) + __builtin_bit_cast(f16x2, gu); \
            t = __builtin_elementwise_fma(ex2, w8, t); \
            t = __builtin_elementwise_fma(ey2, w9, t); \
            t = __builtin_elementwise_max(t, z2); \
            dst = __builtin_bit_cast(unsigned, t) & pz; }
            MSLOT(pa4.x, A1.x, G1.x, w8p[0], w9p[0])
            MSLOT(pa4.y, A1.y, G1.y, w8p[1], w9p[1])
            MSLOT(pa4.z, A1.z, G1.z, w8p[2], w9p[2])
            MSLOT(pa4.w, A1.w, G1.w, w8p[3], w9p[3])
            MSLOT(pb4.x, A2.x, G2.x, w8q[0], w9q[0])
            MSLOT(pb4.y, A2.y, G2.y, w8q[1], w9q[1])
            MSLOT(pb4.z, A2.z, G2.z, w8q[2], w9q[2])
            MSLOT(pb4.w, A2.w, G2.w, w8q[3], w9q[3])
#undef MSLOT
            const f16x8 afA = __builtin_bit_cast(f16x8, pa4);
            const f16x8 afB = __builtin_bit_cast(f16x8, pb4);

            f32x16 c;
#pragma unroll
            for (int j = 0; j < 16; j++) c[j] = 0.0f;
            c = __builtin_amdgcn_mfma_f32_32x32x16_f16(afA, hfA, c, 0, 0, 0);
            c = __builtin_amdgcn_mfma_f32_32x32x16_f16(afB, hfB, c, 0, 0, 0);

            // C: col=lane&31, row=(reg&3)+8*(reg>>2)+4*(lane>>5).
            float sA = ((c[0] + c[1]) + (c[2] + c[3])) + ((c[4] + c[5]) + (c[6] + c[7]));
            float sB = ((c[8] + c[9]) + (c[10] + c[11])) + ((c[12] + c[13]) + (c[14] + c[15]));
            sA += __shfl_xor(sA, 32);
            sB += __shfl_xor(sB, 32);
            const int   nst = (lane < 32) ? tA : tB;
            const float sv  = (lane < 32) ? sA : sB;
            atomicAdd(&xpp[nst * STR + n32], sv);

            p = pn; raw = rawn; tA = tAn; tB = tBn;
        }
    }
    __syncthreads();

    // ---- Stage-P constants (loaded after B to keep stage-B VGPR peak low) ----
    // waves 0-3 produce P1 (Wl[0:36], +bl), waves 4-7 produce P2 (Wl[36:72])
    const bool g1p   = (wv < 4);
    const int  cbase = g1p ? 4 : 40;
    const int  xbase = g1p ? 0 : 36;
    bf16x8 bPa, bPb;
#pragma unroll
    for (int j = 0; j < 8; j++) {
        bPa[j] = f2bf(Wl[(cbase + kh + j) * HID + m16]);
        bPb[j] = f2bf(Wl[(cbase + kh + j) * HID + 16 + m16]);
    }
    float wxa[4], wxb[4];
#pragma unroll
    for (int i = 0; i < 4; i++) {
        wxa[i] = Wl[(xbase + i) * HID + m16];
        wxb[i] = Wl[(xbase + i) * HID + 16 + m16];
    }
    const float bca = g1p ? bl[m16] : 0.f;
    const float bcb = g1p ? bl[16 + m16] : 0.f;
    float b2k[8];
#pragma unroll
    for (int j = 0; j < 8; j++) b2k[j] = b2[kh + j];
    const int   mrow = (wv & 3) * 16 + m16;
    const float dn   = (float)gws[mrow];        // degree from pre-kernel

    // ---- Stage P: head projections via MFMA; outputs packed f16 (cols k,k+16) ----
    {
        const float4* xr = (const float4*)&xpp[mrow * STR + kh];
        float4 x0 = xr[0], x1 = xr[1];
        x0.x = fmaf(dn, b2k[0], x0.x); x0.y = fmaf(dn, b2k[1], x0.y);
        x0.z = fmaf(dn, b2k[2], x0.z); x0.w = fmaf(dn, b2k[3], x0.w);
        x1.x = fmaf(dn, b2k[4], x1.x); x1.y = fmaf(dn, b2k[5], x1.y);
        x1.z = fmaf(dn, b2k[6], x1.z); x1.w = fmaf(dn, b2k[7], x1.w);
        uint4 packed;
        packed.x = pack_bf2(x0.x, x0.y);
        packed.y = pack_bf2(x0.z, x0.w);
        packed.z = pack_bf2(x1.x, x1.y);
        packed.w = pack_bf2(x1.z, x1.w);
        const bf16x8 af = __builtin_bit_cast(bf16x8, packed);

        f32x4 ca, cb;
#pragma unroll
        for (int r = 0; r < 4; r++) {
            const float4 xv = xs4[(wv & 3) * 16 + quad * 4 + r];
            float a0 = bca, a1 = bcb;
#pragma unroll
            for (int i = 0; i < 4; i++) {
                const float xi = (i == 0) ? xv.x : (i == 1) ? xv.y : (i == 2) ? xv.z : xv.w;
                a0 = fmaf(xi, wxa[i], a0);
                a1 = fmaf(xi, wxb[i], a1);
            }
            ca[r] = a0; cb[r] = a1;
        }
        ca = __builtin_amdgcn_mfma_f32_16x16x32_bf16(af, bPa, ca, 0, 0, 0);
        cb = __builtin_amdgcn_mfma_f32_16x16x32_bf16(af, bPb, cb, 0, 0, 0);

        __syncthreads();   // Q-phase f16 reads fully drained before P overwrite
        // P row layout: u32 slot m16 of row holds f16 pair (col m16, col m16+16)
        unsigned* dsth = g1p ? qh0 : qh1;
#pragma unroll
        for (int r = 0; r < 4; r++) {
            const int row = (wv & 3) * 16 + quad * 4 + r;
            dsth[row * QSTRH + m16] = __builtin_bit_cast(unsigned, pkrtz(ca[r], cb[r]));
        }
    }
    __syncthreads();

    // ---- Stage C: per-row combine + value head (packed f16 + dot2) ----
    float vsum = 0.0f;
    {
        const float* actb = action + (size_t)b * NROWS;
        const float bvv = bv[0];
        const float* Wl72 = Wl + 72 * HID;
        f16x2 wlh[16], wvh[16];
#pragma unroll
        for (int j = 0; j < 16; j++) {
            wlh[j] = packh2_rne(Wl72[j], Wl72[j + 16]);
            wvh[j] = packh2_rne(Wv[j],  Wv[j + 16]);
        }

#define CSLOT(j, pu, qu, acc) { \
        f16x2 t = __builtin_bit_cast(f16x2, pu) + __builtin_bit_cast(f16x2, qu); \
        t = __builtin_elementwise_fma(a2, wlh[j], t); \
        t = __builtin_elementwise_max(t, z2); \
        acc = dot2acc(t, wvh[j], acc); }

#define CROW(na, nb, av) { \
        const unsigned* ra = &qh0[(na) * QSTRH]; \
        const unsigned* rb = &qh1[(nb) * QSTRH]; \
        const uint4 Pa0 = *(const uint4*)&ra[0]; \
        const uint4 Pa1 = *(const uint4*)&ra[4]; \
        const uint4 Pa2 = *(const uint4*)&ra[8]; \
        const uint4 Pa3 = *(const uint4*)&ra[12]; \
        const uint4 Pb0 = *(const uint4*)&rb[0]; \
        const uint4 Pb1 = *(const uint4*)&rb[4]; \
        const uint4 Pb2 = *(const uint4*)&rb[8]; \
        const uint4 Pb3 = *(const uint4*)&rb[12]; \
        const f16x2 a2 = pkrtz(av, av); \
        float v0 = bvv, v1 = 0.0f; \
        CSLOT( 0, Pa0.x, Pb0.x, v0) CSLOT( 1, Pa0.y, Pb0.y, v1) \
        CSLOT( 2, Pa0.z, Pb0.z, v0) CSLOT( 3, Pa0.w, Pb0.w, v1) \
        CSLOT( 4, Pa1.x, Pb1.x, v0) CSLOT( 5, Pa1.y, Pb1.y, v1) \
        CSLOT( 6, Pa1.z, Pb1.z, v0) CSLOT( 7, Pa1.w, Pb1.w, v1) \
        CSLOT( 8, Pa2.x, Pb2.x, v0) CSLOT( 9, Pa2.y, Pb2.y, v1) \
        CSLOT(10, Pa2.z, Pb2.z, v0) CSLOT(11, Pa2.w, Pb2.w, v1) \
        CSLOT(12, Pa3.x, Pb3.x, v0) CSLOT(13, Pa3.y, Pb3.y, v1) \
        CSLOT(14, Pa3.z, Pb3.z, v0) CSLOT(15, Pa3.w, Pb3.w, v1) \
        vsum += v0 + v1; }

#pragma unroll 1
        for (int i = 0; i < EPT; i++) {
            const int na = ces[i], nb = ced[i];
            const float a = actb[tid + i * TPB];
            CROW(na, nb, a)
        }
        // factory rows 1024..1026 (na == nb)
        if (tid < NFACT) {
            const int r = NE + tid;
            const int naf = NNODES - NFACT + tid;
            const float av = actb[r];
            CROW(naf, naf, av)
        }
#undef CROW
#undef CSLOT
    }

    // ---- block reduction ----
#pragma unroll
    for (int off = 32; off > 0; off >>= 1)
        vsum += __shfl_down(vsum, off, 64);
    if ((tid & 63) == 0) wred[tid >> 6] = vsum;
    __syncthreads();
    if (tid == 0) {
        float t = 0.0f;
#pragma unroll
        for (int w = 0; w < TPB / 64; w++) t += wred[w];
        out[b] = t;
    }
}

extern "C" void kernel_launch(void* const* d_in, const int* in_sizes, int n_in,
                              void* d_out, int out_size, void* d_ws, size_t ws_size,
                              hipStream_t stream) {
    const float* x         = (const float*)d_in[0];
    const float* edge_attr = (const float*)d_in[2];
    const float* action    = (const float*)d_in[3];
    const int*   es        = (const int*)d_in[4];
    const int*   ed        = (const int*)d_in[5];
    const float* W1        = (const float*)d_in[6];
    const float* b1        = (const float*)d_in[7];
    const float* W2        = (const float*)d_in[8];
    const float* b2        = (const float*)d_in[9];
    const float* Wl        = (const float*)d_in[10];
    const float* bl        = (const float*)d_in[11];
    const float* Wv        = (const float*)d_in[12];
    const float* bv        = (const float*)d_in[13];
    float* out = (float*)d_out;
    int*   gws = (int*)d_ws;   // needs 2560 ints = 10.2KB

    csr_build<<<dim3(1), dim3(256), 0, stream>>>(es, ed, gws);
    critic_fused<<<dim3(out_size), dim3(TPB), 0, stream>>>(
        x, edge_attr, action, es, ed, W1, b1, W2, b2, Wl, bl, Wv, bv, gws, out);
}